// Round 9
// baseline (404.779 us; speedup 1.0000x reference)
//
#include <hip/hip_runtime.h>
#include <hip/hip_bf16.h>
#include <stdint.h>

typedef unsigned short u16;
typedef _Float16 f16;
typedef short vs8 __attribute__((ext_vector_type(8)));   // 8 x bf16 bits (MFMA A/B frag)
typedef float vf4 __attribute__((ext_vector_type(4)));   // MFMA C/D frag
typedef _Float16 vh2 __attribute__((ext_vector_type(2)));
typedef _Float16 vh4 __attribute__((ext_vector_type(4)));
typedef _Float16 vh8 __attribute__((ext_vector_type(8)));
typedef __fp16 hw2 __attribute__((ext_vector_type(2)));  // cvt_pkrtz return type

// Problem constants: B=4 T=2048 E=256 H=8 HD=32 FE=4 L=4
//
// Ledger: R16 LDS swizzle -39us (conflict removal). R14 combine-fusion -20us (traffic).
// R13/R15/R17/R18/R19/R20: occupancy/scheduling/fusion/XCD tweaks all null or regressed
// on this L3-resident workload. Only traffic & conflict removal ever pay.
// R21: remove the kv-split partial round-trip (R13's split-2 occupancy theory was disproven
// in-round; its 12MB/layer partial traffic remained). attn back to split-1: normalize
// in-register (lO row-aligned with O), write bf16 attnB (4MB) directly; LN1 A-path becomes
// plain gload16. Saves ~50MB total L2/L3 traffic + LN1's double-read/pack combine work.

__device__ __forceinline__ void gload16(const u16* g, u16* l) {
  __builtin_amdgcn_global_load_lds((const __attribute__((address_space(1))) void*)g,
                                   (__attribute__((address_space(3))) void*)l,
                                   16, 0, 0);
}

__device__ __forceinline__ float fexp2(float x) {
#if __has_builtin(__builtin_amdgcn_exp2f)
  return __builtin_amdgcn_exp2f(x);
#else
  return __expf(x * 0.69314718056f);
#endif
}

// ---------------- merged: Fourier PE (blocks 0..2047) + weight transpose (blocks 2048..5119) ----------------
__global__ void pe_trans_all(
    const float* __restrict__ x, __hip_bfloat16* __restrict__ Xb,
    const float* __restrict__ w0, const float* __restrict__ w1,
    const float* __restrict__ w2, const float* __restrict__ w3,
    u16* __restrict__ o0, u16* __restrict__ o1,
    u16* __restrict__ o2, u16* __restrict__ o3) {
  __shared__ float tile[32][33];
  int bid = blockIdx.x;
  int tid = threadIdx.x;
  if (bid < 2048) {
    // ---- Fourier PE -> bf16 (fast trig: exp2 + hw sin/cos in revolutions)
    int gid = bid * 256 + tid;                   // 0..524287
    int row = gid >> 6;                          // 0..8191 (64 thr/row, 4 elems each)
    int e0 = (gid & 63) * 4;                     // 0..252, 4-aligned; same side of 128
    int t = row & 2047;
    int f0 = (e0 < 128) ? e0 : (e0 - 128);
    const float c = -13.287712379549449f / 128.0f;   // -log2(10000)/128
    const float inv2pi = 0.15915494309189535f;
    float4 xv = *(const float4*)(x + (size_t)row * 256 + e0);
    u16 o[4];
#pragma unroll
    for (int j = 0; j < 4; ++j) {
      float freq = fexp2(c * (float)(f0 + j));
      float rev = (float)t * freq * inv2pi;
      rev = rev - floorf(rev);
      float pe = (e0 < 128) ? __builtin_amdgcn_sinf(rev) : __builtin_amdgcn_cosf(rev);
      float xin = (j == 0) ? xv.x : (j == 1) ? xv.y : (j == 2) ? xv.z : xv.w;
      __hip_bfloat16 hb = __float2bfloat16(xin + pe);
      o[j] = *(u16*)&hb;
    }
    *(uint2*)((u16*)Xb + (size_t)row * 256 + e0) = *(uint2*)o;
  } else {
    // ---- weight transpose + cast: f32 [L][K][N] -> bf16 [L][N][K]
    int flat = bid - 2048;                 // 0..3071
    int layer = flat / 768;
    int r = flat - layer * 768;
    const float* ip; u16* op; int K, N, kt, nt;
    if (r < 192)      {              ip = w0; op = o0; K = 256;  N = 768;  kt = r & 7;  nt = r >> 3; }
    else if (r < 256) { int q=r-192; ip = w1; op = o1; K = 256;  N = 256;  kt = q & 7;  nt = q >> 3; }
    else if (r < 512) { int q=r-256; ip = w2; op = o2; K = 256;  N = 1024; kt = q & 7;  nt = q >> 3; }
    else              { int q=r-512; ip = w3; op = o3; K = 1024; N = 256;  kt = q & 31; nt = q >> 5; }
    ip += (size_t)layer * K * N;
    op += (size_t)layer * N * K;
    int k0 = kt * 32, n0 = nt * 32;
    int tx = tid & 31, ty = tid >> 5;      // (32,8)
#pragma unroll
    for (int rr = 0; rr < 4; ++rr) {
      int k = ty + rr * 8;
      tile[k][tx] = ip[(size_t)(k0 + k) * N + (n0 + tx)];
    }
    __syncthreads();
#pragma unroll
    for (int rr = 0; rr < 4; ++rr) {
      int n = ty + rr * 8;
      __hip_bfloat16 v = __float2bfloat16(tile[tx][n]);
      op[(size_t)(n0 + n) * K + (k0 + tx)] = *(u16*)&v;
    }
  }
}

// ---------------- bf16 MFMA GEMM 128x128, BK=64, LDS-swizzled, XCD-chunked (ff1) ----------------
__global__ __launch_bounds__(256, 2) void gemm_relu(
    const u16* __restrict__ A, const u16* __restrict__ Bt,
    const float* __restrict__ bias, __hip_bfloat16* __restrict__ outB,
    int M, int N, int K) {
  __shared__ u16 As[128 * 64];
  __shared__ u16 Bs[128 * 64];
  int tid = threadIdx.x;
  int wave = tid >> 6, lane = tid & 63;
  int wm = wave & 1, wn = wave >> 1;              // 2x2 waves of 64x64
  int flat = blockIdx.x + blockIdx.y * 8;
  int logical = (flat & 7) * 64 + (flat >> 3);
  int m0 = (logical >> 3) * 128, n0 = (logical & 7) * 128;
  int lr = lane & 15, lq = lane >> 4;
  int swz = (lr & 7) << 3;                        // read-side XOR (elems)

  vf4 acc[4][4];
#pragma unroll
  for (int i = 0; i < 4; ++i)
#pragma unroll
    for (int j = 0; j < 4; ++j) {
      acc[i][j][0] = 0.f; acc[i][j][1] = 0.f; acc[i][j][2] = 0.f; acc[i][j][3] = 0.f;
    }

  int srow = tid >> 3;                  // 0..31 (+32*r rounds; &7 invariant)
  int sc = (tid & 7) * 8;               // linear LDS dest col (elems)
  int cswz = (((tid & 7) ^ (srow & 7)) * 8);   // pre-swizzled GLOBAL source col
  const u16* ag = A + (size_t)(m0 + srow) * K + cswz;
  const u16* bg = Bt + (size_t)(n0 + srow) * K + cswz;
  u16* al = As + srow * 64 + sc;
  u16* bl = Bs + srow * 64 + sc;
  const size_t rstride32 = (size_t)32 * K;

  for (int k0 = 0; k0 < K; k0 += 64) {
#pragma unroll
    for (int r = 0; r < 4; ++r) {
      gload16(ag + k0 + r * rstride32, al + r * 32 * 64);
      gload16(bg + k0 + r * rstride32, bl + r * 32 * 64);
    }
    __syncthreads();
#pragma unroll
    for (int kk = 0; kk < 2; ++kk) {
      vs8 av[4], bv[4];
#pragma unroll
      for (int i = 0; i < 4; ++i)
        av[i] = *(const vs8*)&As[(wm * 64 + i * 16 + lr) * 64 + ((kk * 32 + lq * 8) ^ swz)];
#pragma unroll
      for (int j = 0; j < 4; ++j)
        bv[j] = *(const vs8*)&Bs[(wn * 64 + j * 16 + lr) * 64 + ((kk * 32 + lq * 8) ^ swz)];
#pragma unroll
      for (int i = 0; i < 4; ++i)
#pragma unroll
        for (int j = 0; j < 4; ++j)
          acc[i][j] = __builtin_amdgcn_mfma_f32_16x16x32_bf16(av[i], bv[j], acc[i][j], 0, 0, 0);
    }
    __syncthreads();
  }

#pragma unroll
  for (int i = 0; i < 4; ++i) {
    int row0 = m0 + wm * 64 + i * 16 + lq * 4;
#pragma unroll
    for (int j = 0; j < 4; ++j) {
      int col = n0 + wn * 64 + j * 16 + lr;
      float bb = bias[col];
#pragma unroll
      for (int r = 0; r < 4; ++r) {
        size_t idx = (size_t)(row0 + r) * N + col;
        outB[idx] = __float2bfloat16(fmaxf(acc[i][j][r] + bb, 0.0f));
      }
    }
  }
}

// ---------------- bf16 MFMA GEMM 64x128, BK=64, LDS-swizzled, XCD-chunked (qkv) ----------------
__global__ __launch_bounds__(256, 3) void gemm_qkv64(
    const u16* __restrict__ A, const u16* __restrict__ Bt,
    const float* __restrict__ bias, f16* __restrict__ outH,
    int M, int N, int K) {
  __shared__ u16 As[64 * 64];
  __shared__ u16 Bs[128 * 64];
  int tid = threadIdx.x;
  int wave = tid >> 6, lane = tid & 63;
  int wm = wave & 1, wn = wave >> 1;              // wave = 32 rows x 64 cols
  int flat = blockIdx.x + blockIdx.y * 6;
  int logical = (flat & 7) * 96 + (flat >> 3);
  int ly = logical / 6, lx = logical - ly * 6;
  int m0 = ly * 64, n0 = lx * 128;
  int lr = lane & 15, lq = lane >> 4;
  int swz = (lr & 7) << 3;

  vf4 acc[2][4];
#pragma unroll
  for (int i = 0; i < 2; ++i)
#pragma unroll
    for (int j = 0; j < 4; ++j) { acc[i][j][0]=0.f; acc[i][j][1]=0.f; acc[i][j][2]=0.f; acc[i][j][3]=0.f; }

  int srow = tid >> 3;                  // 0..31
  int sc = (tid & 7) * 8;
  int cswz = (((tid & 7) ^ (srow & 7)) * 8);
  const u16* ag = A + (size_t)(m0 + srow) * K + cswz;
  const u16* bg = Bt + (size_t)(n0 + srow) * K + cswz;
  u16* al = As + srow * 64 + sc;
  u16* bl = Bs + srow * 64 + sc;
  const size_t rstride32 = (size_t)32 * K;

  for (int k0 = 0; k0 < K; k0 += 64) {
#pragma unroll
    for (int r = 0; r < 2; ++r)
      gload16(ag + k0 + r * rstride32, al + r * 32 * 64);
#pragma unroll
    for (int r = 0; r < 4; ++r)
      gload16(bg + k0 + r * rstride32, bl + r * 32 * 64);
    __syncthreads();
#pragma unroll
    for (int kk = 0; kk < 2; ++kk) {
      vs8 av[2], bv[4];
#pragma unroll
      for (int i = 0; i < 2; ++i)
        av[i] = *(const vs8*)&As[(wm * 32 + i * 16 + lr) * 64 + ((kk * 32 + lq * 8) ^ swz)];
#pragma unroll
      for (int j = 0; j < 4; ++j)
        bv[j] = *(const vs8*)&Bs[(wn * 64 + j * 16 + lr) * 64 + ((kk * 32 + lq * 8) ^ swz)];
#pragma unroll
      for (int i = 0; i < 2; ++i)
#pragma unroll
        for (int j = 0; j < 4; ++j)
          acc[i][j] = __builtin_amdgcn_mfma_f32_16x16x32_bf16(av[i], bv[j], acc[i][j], 0, 0, 0);
    }
    __syncthreads();
  }

#pragma unroll
  for (int i = 0; i < 2; ++i) {
    int row0 = m0 + wm * 32 + i * 16 + lq * 4;
#pragma unroll
    for (int j = 0; j < 4; ++j) {
      int col = n0 + wn * 64 + j * 16 + lr;
      float bb = bias[col];
#pragma unroll
      for (int r = 0; r < 4; ++r)
        outH[(size_t)(row0 + r) * N + col] = (f16)(acc[i][j][r] + bb);
    }
  }
}

// ---------------- fused GEMM (N=256) + bias + bf16 residual + LN -> bf16 (+f32 opt) ----------------
// 16 rows/block, 256 threads (4 waves, wn 0..3; wave = 16 rows x 64 cols), grid 512 =
// 2 blocks/CU. BK=64 simple barrier loop, XOR-swizzled tiles. A is always a plain bf16
// matrix now (R21: attn writes normalized attnB directly; combine path removed).
__global__ __launch_bounds__(256, 2) void gemm_ln(
    const u16* __restrict__ A, const u16* __restrict__ Bt,
    const float* __restrict__ bias, const __hip_bfloat16* __restrict__ res,
    const float* __restrict__ gam, const float* __restrict__ bet,
    __hip_bfloat16* __restrict__ outB, float* __restrict__ outF, int K) {
  __shared__ u16 As[16 * 64];
  __shared__ u16 Bs[256 * 64];
  __shared__ float ps[4][16], ps2[4][16], mur[16], rsr[16];
  int tid = threadIdx.x;
  int wave = tid >> 6, lane = tid & 63;
  int wn = wave;                                   // 0..3 (single row-group)
  int lr = lane & 15, lq = lane >> 4;
  int m0 = blockIdx.x * 16;
  int swz = (lr & 7) << 3;

  vf4 acc[4];
#pragma unroll
  for (int j = 0; j < 4; ++j) { acc[j][0]=0.f; acc[j][1]=0.f; acc[j][2]=0.f; acc[j][3]=0.f; }

  // A-staging: 16 rows x 64 cols/step = 128 vh8 -> tid<128
  int srA = tid >> 3;                   // 0..31 (A uses 0..15 via tid<128)
  int scA = (tid & 7) * 8;
  int cswzA = (((tid & 7) ^ (srA & 7)) * 8);
  const u16* ag = A + (size_t)(m0 + srA) * K + cswzA;
  u16* al = As + srA * 64 + scA;
  // B-staging: 256 rows x 64 cols/step = 2048 vh8 -> 8 rounds of 32 rows
  const u16* bg = Bt + (size_t)srA * K + cswzA;   // rows srA + 32*r; (srA+32r)&7 == srA&7
  u16* bl = Bs + srA * 64 + scA;

  for (int k0 = 0; k0 < K; k0 += 64) {
    if (tid < 128) gload16(ag + k0, al);
#pragma unroll
    for (int r = 0; r < 8; ++r)
      gload16(bg + k0 + (size_t)(r * 32) * K, bl + r * 32 * 64);
    __syncthreads();
#pragma unroll
    for (int kk = 0; kk < 2; ++kk) {
      vs8 av, bv[4];
      av = *(const vs8*)&As[lr * 64 + ((kk * 32 + lq * 8) ^ swz)];
#pragma unroll
      for (int j = 0; j < 4; ++j)
        bv[j] = *(const vs8*)&Bs[(wn * 64 + j * 16 + lr) * 64 + ((kk * 32 + lq * 8) ^ swz)];
#pragma unroll
      for (int j = 0; j < 4; ++j)
        acc[j] = __builtin_amdgcn_mfma_f32_16x16x32_bf16(av, bv[j], acc[j], 0, 0, 0);
    }
    __syncthreads();
  }

  float sum_[4], sq_[4];
#pragma unroll
  for (int r = 0; r < 4; ++r) { sum_[r] = 0.f; sq_[r] = 0.f; }
#pragma unroll
  for (int j = 0; j < 4; ++j) {
    int col = wn * 64 + j * 16 + lr;
    float bb = bias[col];
#pragma unroll
    for (int r = 0; r < 4; ++r) {
      int row = m0 + lq * 4 + r;
      float v = acc[j][r] + bb + __bfloat162float(res[(size_t)row * 256 + col]);
      acc[j][r] = v;
      sum_[r] += v;
      sq_[r] += v * v;
    }
  }
#pragma unroll
  for (int r = 0; r < 4; ++r) {
#pragma unroll
    for (int m = 1; m <= 8; m <<= 1) {
      sum_[r] += __shfl_xor(sum_[r], m);
      sq_[r]  += __shfl_xor(sq_[r], m);
    }
  }
  if (lr == 0) {
#pragma unroll
    for (int r = 0; r < 4; ++r) {
      int rl = lq * 4 + r;
      ps[wn][rl] = sum_[r];
      ps2[wn][rl] = sq_[r];
    }
  }
  __syncthreads();
  if (tid < 16) {
    float s = ps[0][tid] + ps[1][tid] + ps[2][tid] + ps[3][tid];
    float s2 = ps2[0][tid] + ps2[1][tid] + ps2[2][tid] + ps2[3][tid];
    float mu = s * (1.0f / 256.0f);
    float var = s2 * (1.0f / 256.0f) - mu * mu;
    mur[tid] = mu;
    rsr[tid] = rsqrtf(var + 1e-5f);
  }
  __syncthreads();
#pragma unroll
  for (int r = 0; r < 4; ++r) {
    int rl = lq * 4 + r;
    float mu = mur[rl], rs = rsr[rl];
    int row = m0 + rl;
#pragma unroll
    for (int j = 0; j < 4; ++j) {
      int col = wn * 64 + j * 16 + lr;
      float o = (acc[j][r] - mu) * rs * gam[col] + bet[col];
      size_t idx = (size_t)row * 256 + col;
      outB[idx] = __float2bfloat16(o);
      if (outF) outF[idx] = o;
    }
  }
}

// ---------------- MFMA flash attention v8: split-1, in-register normalize -> bf16 ----------------
// R21: kv-split removed (R13's occupancy theory was disproven; its partial traffic cost
// stayed). 16 kv-chunks of 128 rows, double-buffered; lO row-aligned with O -> normalize
// in-register, write bf16 attnB directly. Grid 256 XCD-pinned, 8 waves.
__global__ __launch_bounds__(512, 4) void attn_mfma(const f16* __restrict__ qkv,
                                                    __hip_bfloat16* __restrict__ out) {
  // per buf: K [128][40] u16 = 5120 | VT [32][132] f16 = 4224 -> 9344 u16; x2 bufs = 37376 B
  __shared__ __align__(16) u16 lds[2][9344];
  int tid = threadIdx.x;
  int wave = tid >> 6, lane = tid & 63;
  int lr = lane & 15, quad = lane >> 4;

  int id = blockIdx.x;
  int xcd = id & 7, slot = id >> 3;                // slot 0..31
  int grp = xcd * 4 + (slot & 3);                  // 32 (b,h) groups
  int qt = slot >> 2;                              // 8 q-tiles of 256 rows
  int b = grp >> 3, h = grp & 7;
  int q0 = qt * 256;
  int rowbase = b * 2048;
  const f16* base_bh = qkv + (size_t)rowbase * 768 + h * 96;

  vh8 qf[2];
#pragma unroll
  for (int nt = 0; nt < 2; ++nt) {
    int qr = q0 + wave * 32 + nt * 16 + lr;
    vh8 t = *(const vh8*)(base_bh + (size_t)qr * 768 + quad * 8);
#pragma unroll
    for (int j = 0; j < 8; ++j) t[j] = t[j] * (f16)0.25508682f;
    qf[nt] = t;
  }

  vf4 O[2][2], lO[2];
#pragma unroll
  for (int a = 0; a < 2; ++a) {
    lO[a][0]=0.f; lO[a][1]=0.f; lO[a][2]=0.f; lO[a][3]=0.f;
#pragma unroll
    for (int d = 0; d < 2; ++d) { O[a][d][0]=0.f; O[a][d][1]=0.f; O[a][d][2]=0.f; O[a][d][3]=0.f; }
  }

  // staging maps: all 512 threads stage K (1 vh8) and V (2 vh4 -> 4 vh2) per chunk
  int srK = tid >> 2;                  // 0..127
  int scK = (tid & 3) * 8;
  const f16* kg = base_bh + (size_t)srK * 768 + 32 + scK;
  int kvp = tid >> 3;                  // 0..63 -> rows 2kvp, 2kvp+1
  int d4 = (tid & 7) * 4;
  const f16* vg = base_bh + (size_t)(kvp * 2) * 768 + 64 + d4;

  const vf4 z4 = {0.f, 0.f, 0.f, 0.f};
  const vh4 onesh = {(f16)1.0f, (f16)1.0f, (f16)1.0f, (f16)1.0f};
  const size_t cstep = (size_t)128 * 768;

  // stage chunk 0 into buf 0
  {
    vh8 k0 = *(const vh8*)kg;
    *(vh8*)&lds[0][srK * 40 + scK] = k0;
    vh4 a = *(const vh4*)vg;
    vh4 bb = *(const vh4*)(vg + 768);
    f16* vt0 = (f16*)&lds[0][5120];
#pragma unroll
    for (int i = 0; i < 4; ++i) {
      vh2 pr; pr[0] = a[i]; pr[1] = bb[i];
      *(vh2*)(vt0 + (d4 + i) * 132 + kvp * 2) = pr;
    }
  }
  __syncthreads();

  for (int c = 0; c < 16; ++c) {       // 16 chunks of 128 kv rows
    int cur = c & 1;
    const f16* Ks = (const f16*)&lds[cur][0];
    const f16* VT = (const f16*)&lds[cur][5120];

    vh8 kn; vh4 va, vb;
    if (c < 15) {                      // prefetch next chunk (hidden under 8-t16 compute)
      kn = *(const vh8*)(kg + (size_t)(c + 1) * cstep);
      const f16* vp = vg + (size_t)(c + 1) * cstep;
      va = *(const vh4*)vp;
      vb = *(const vh4*)(vp + 768);
    }

    __builtin_amdgcn_s_setprio(1);     // T5: favor this wave while in the MFMA/exp cluster
#pragma unroll
    for (int t16 = 0; t16 < 8; ++t16) {
      vh8 ak = *(const vh8*)&Ks[(t16 * 16 + lr) * 40 + quad * 8];
      vf4 s0 = __builtin_amdgcn_mfma_f32_16x16x32_f16(ak, qf[0], z4, 0, 0, 0);
      vf4 s1 = __builtin_amdgcn_mfma_f32_16x16x32_f16(ak, qf[1], z4, 0, 0, 0);
      vh4 p0, p1;
      ((hw2*)&p0)[0] = __builtin_amdgcn_cvt_pkrtz(fexp2(s0[0]), fexp2(s0[1]));
      ((hw2*)&p0)[1] = __builtin_amdgcn_cvt_pkrtz(fexp2(s0[2]), fexp2(s0[3]));
      ((hw2*)&p1)[0] = __builtin_amdgcn_cvt_pkrtz(fexp2(s1[0]), fexp2(s1[1]));
      ((hw2*)&p1)[1] = __builtin_amdgcn_cvt_pkrtz(fexp2(s1[2]), fexp2(s1[3]));
      vh4 vf0 = *(const vh4*)&VT[(0 * 16 + lr) * 132 + t16 * 16 + quad * 4];
      vh4 vf1 = *(const vh4*)&VT[(1 * 16 + lr) * 132 + t16 * 16 + quad * 4];
      O[0][0] = __builtin_amdgcn_mfma_f32_16x16x16f16(p0, vf0, O[0][0], 0, 0, 0);
      O[0][1] = __builtin_amdgcn_mfma_f32_16x16x16f16(p0, vf1, O[0][1], 0, 0, 0);
      O[1][0] = __builtin_amdgcn_mfma_f32_16x16x16f16(p1, vf0, O[1][0], 0, 0, 0);
      O[1][1] = __builtin_amdgcn_mfma_f32_16x16x16f16(p1, vf1, O[1][1], 0, 0, 0);
      lO[0] = __builtin_amdgcn_mfma_f32_16x16x16f16(p0, onesh, lO[0], 0, 0, 0);
      lO[1] = __builtin_amdgcn_mfma_f32_16x16x16f16(p1, onesh, lO[1], 0, 0, 0);
    }
    __builtin_amdgcn_s_setprio(0);

    if (c < 15) {                      // write prefetched chunk into the other buffer
      *(vh8*)&lds[cur ^ 1][srK * 40 + scK] = kn;
      f16* vt1 = (f16*)&lds[cur ^ 1][5120];
#pragma unroll
      for (int i = 0; i < 4; ++i) {
        vh2 pr; pr[0] = va[i]; pr[1] = vb[i];
        *(vh2*)(vt1 + (d4 + i) * 132 + kvp * 2) = pr;
      }
    }
    __syncthreads();
  }

  // epilogue: l lane-aligned with O (row q = quad*4+r) -> normalize in-register, write bf16
#pragma unroll
  for (int nt = 0; nt < 2; ++nt) {
#pragma unroll
    for (int r = 0; r < 4; ++r) {
      float inv = 1.0f / lO[nt][r];
      int row = rowbase + q0 + wave * 32 + nt * 16 + quad * 4 + r;
#pragma unroll
      for (int dt = 0; dt < 2; ++dt) {
        int col = h * 32 + dt * 16 + lr;
        out[(size_t)row * 256 + col] = __float2bfloat16(O[nt][dt][r] * inv);
      }
    }
  }
}

// ---------------- driver ----------------
extern "C" void kernel_launch(void* const* d_in, const int* in_sizes, int n_in,
                              void* d_out, int out_size, void* d_ws, size_t ws_size,
                              hipStream_t stream) {
  (void)in_sizes; (void)n_in; (void)out_size; (void)ws_size;
  const float* x     = (const float*)d_in[0];
  const float* qkv_b = (const float*)d_in[2];
  const float* out_b = (const float*)d_in[4];
  const float* ff1_b = (const float*)d_in[6];
  const float* ff2_b = (const float*)d_in[8];
  const float* ln1_g = (const float*)d_in[9];
  const float* ln1_b = (const float*)d_in[10];
  const float* ln2_g = (const float*)d_in[11];
  const float* ln2_b = (const float*)d_in[12];

  // ws layout (bytes); total = 44,040,192
  //   [0, 4194304)          attnB bf16 8192x256 (4 MB)
  //   [8388608, 12582912)   Xb: bf16 carried state (4 MB)
  //   [25165824, 37748736)  qkvH f16 8192x768 (12.6 MB)
  //   [20971520, 37748736)  hB bf16 ff1-out (16.8 MB) overlaps qkvH (dead by ff1)
  //   [37748736, 44040192)  transposed bf16 weights
  char* ws = (char*)d_ws;
  __hip_bfloat16* attnB = (__hip_bfloat16*)(ws + 0);
  __hip_bfloat16* Xb    = (__hip_bfloat16*)(ws + 8388608);
  f16*            qkvH  = (f16*)(ws + 25165824);
  __hip_bfloat16* hB    = (__hip_bfloat16*)(ws + 20971520);
  u16* qkvwT = (u16*)(ws + 37748736);  // [L][768][256] bf16
  u16* outwT = (u16*)(ws + 39321600);  // [L][256][256] bf16
  u16* ff1wT = (u16*)(ws + 39845888);  // [L][1024][256] bf16
  u16* ff2wT = (u16*)(ws + 41943040);  // [L][256][1024] bf16  ends 44,040,192

  pe_trans_all<<<5120, 256, 0, stream>>>(x, Xb,
      (const float*)d_in[1], (const float*)d_in[3], (const float*)d_in[5], (const float*)d_in[7],
      qkvwT, outwT, ff1wT, ff2wT);

  for (int l = 0; l < 4; ++l) {
    // qkv = x @ qkv_w + b -> f16 (64x128 tile, 768 blocks = 3/CU, XCD-chunked)
    gemm_qkv64<<<dim3(6, 128), 256, 0, stream>>>((const u16*)Xb, qkvwT + (size_t)l * 768 * 256,
        qkv_b + l * 768, qkvH, 8192, 768, 256);
    // attn -> normalized bf16 attnB (split-1, grid 256 XCD-pinned)
    attn_mfma<<<256, 512, 0, stream>>>(qkvH, attnB);
    // Xb = LN1(attnB @ out_w + b + Xb); 16-row blocks, 2 blocks/CU
    gemm_ln<<<512, 256, 0, stream>>>((const u16*)attnB, outwT + (size_t)l * 256 * 256,
        out_b + l * 256, Xb, ln1_g + l * 256, ln1_b + l * 256, Xb, nullptr, 256);
    // h = relu(Xb @ W1 + b1) -> bf16 (XCD-chunked)
    gemm_relu<<<dim3(8, 64), 256, 0, stream>>>((const u16*)Xb, ff1wT + (size_t)l * 1024 * 256,
        ff1_b + l * 1024, hB, 8192, 1024, 256);
    // Xb = LN2(h @ W2 + b2 + Xb); last layer also writes d_out f32; 16-row blocks
    float* lnout = (l == 3) ? (float*)d_out : nullptr;
    gemm_ln<<<512, 256, 0, stream>>>((const u16*)hB, ff2wT + (size_t)l * 256 * 1024,
        ff2_b + l * 256, Xb, ln2_g + l * 256, ln2_b + l * 256, Xb, lnout, 1024);
  }
}

// Round 10
// 389.089 us; speedup vs baseline: 1.0403x; 1.0403x over previous
//
#include <hip/hip_runtime.h>
#include <hip/hip_bf16.h>
#include <stdint.h>

typedef unsigned short u16;
typedef _Float16 f16;
typedef short vs8 __attribute__((ext_vector_type(8)));   // 8 x bf16 bits (MFMA A/B frag)
typedef float vf4 __attribute__((ext_vector_type(4)));   // MFMA C/D frag
typedef _Float16 vh2 __attribute__((ext_vector_type(2)));
typedef _Float16 vh4 __attribute__((ext_vector_type(4)));
typedef _Float16 vh8 __attribute__((ext_vector_type(8)));
typedef __fp16 hw2 __attribute__((ext_vector_type(2)));  // cvt_pkrtz return type

// Problem constants: B=4 T=2048 E=256 H=8 HD=32 FE=4 L=4
//
// R22: REVERT to best measured build (R19, 401.4 us). Session ledger:
//   paid:  R14 fusion/launch-count -20us; R16 LDS XOR-swizzle -39us.
//   null:  R13 kv-split occupancy, R15 BK=64, R19 gemm_ln 2-blk/CU, R20 XCD chunk,
//          R21 kv-split-removal (traffic not the limit; L3-resident workload).
//   negative: R17 counted-vmcnt graft (+33), R18 LN+GEMM serial fusion (+36).
// Plateau 401-405 across six builds; remaining gap = per-dispatch ramp + exp-bound attn
// (64 v_exp_f32/wave/chunk ~ 8us/dispatch floor) + shallow-K GEMM latency.

__device__ __forceinline__ void gload16(const u16* g, u16* l) {
  __builtin_amdgcn_global_load_lds((const __attribute__((address_space(1))) void*)g,
                                   (__attribute__((address_space(3))) void*)l,
                                   16, 0, 0);
}

__device__ __forceinline__ float fexp2(float x) {
#if __has_builtin(__builtin_amdgcn_exp2f)
  return __builtin_amdgcn_exp2f(x);
#else
  return __expf(x * 0.69314718056f);
#endif
}

// ---------------- Fourier PE -> bf16 (fast trig: exp2 + hw sin/cos in revolutions) ----------------
__global__ void pe_kernel(const float* __restrict__ x, __hip_bfloat16* __restrict__ Xb) {
  int gid = blockIdx.x * 256 + threadIdx.x;   // 0..524287
  int row = gid >> 6;                          // 0..8191 (64 thr/row, 4 elems each)
  int e0 = (gid & 63) * 4;                     // 0..252, 4-aligned; same side of 128
  int t = row & 2047;
  int f0 = (e0 < 128) ? e0 : (e0 - 128);
  const float c = -13.287712379549449f / 128.0f;   // -log2(10000)/128
  const float inv2pi = 0.15915494309189535f;
  float4 xv = *(const float4*)(x + (size_t)row * 256 + e0);
  u16 o[4];
#pragma unroll
  for (int j = 0; j < 4; ++j) {
    float freq = fexp2(c * (float)(f0 + j));
    float rev = (float)t * freq * inv2pi;
    rev = rev - floorf(rev);
    float pe = (e0 < 128) ? __builtin_amdgcn_sinf(rev) : __builtin_amdgcn_cosf(rev);
    float xin = (j == 0) ? xv.x : (j == 1) ? xv.y : (j == 2) ? xv.z : xv.w;
    __hip_bfloat16 hb = __float2bfloat16(xin + pe);
    o[j] = *(u16*)&hb;
  }
  *(uint2*)((u16*)Xb + (size_t)row * 256 + e0) = *(uint2*)o;
}

// ---------------- merged weight transpose + cast: f32 [L][K][N] -> bf16 [L][N][K] ----------------
__global__ void transpose_cast_all(
    const float* __restrict__ w0, const float* __restrict__ w1,
    const float* __restrict__ w2, const float* __restrict__ w3,
    u16* __restrict__ o0, u16* __restrict__ o1,
    u16* __restrict__ o2, u16* __restrict__ o3) {
  __shared__ float tile[32][33];
  int flat = blockIdx.x;                 // 0..3071
  int layer = flat / 768;
  int r = flat - layer * 768;
  const float* ip; u16* op; int K, N, kt, nt;
  if (r < 192)      {              ip = w0; op = o0; K = 256;  N = 768;  kt = r & 7;  nt = r >> 3; }  // qkv 8x24
  else if (r < 256) { int q=r-192; ip = w1; op = o1; K = 256;  N = 256;  kt = q & 7;  nt = q >> 3; }  // out 8x8
  else if (r < 512) { int q=r-256; ip = w2; op = o2; K = 256;  N = 1024; kt = q & 7;  nt = q >> 3; }  // ff1 8x32
  else              { int q=r-512; ip = w3; op = o3; K = 1024; N = 256;  kt = q & 31; nt = q >> 5; }  // ff2 32x8
  ip += (size_t)layer * K * N;
  op += (size_t)layer * N * K;
  int k0 = kt * 32, n0 = nt * 32;
  int tx = threadIdx.x, ty = threadIdx.y;   // (32,8)
#pragma unroll
  for (int rr = 0; rr < 4; ++rr) {
    int k = ty + rr * 8;
    tile[k][tx] = ip[(size_t)(k0 + k) * N + (n0 + tx)];
  }
  __syncthreads();
#pragma unroll
  for (int rr = 0; rr < 4; ++rr) {
    int n = ty + rr * 8;
    __hip_bfloat16 v = __float2bfloat16(tile[tx][n]);
    op[(size_t)(n0 + n) * K + (k0 + tx)] = *(u16*)&v;
  }
}

// ---------------- bf16 MFMA GEMM 128x128, BK=64, LDS-swizzled (ff1): relu(A@W+b) -> bf16 ----------------
__global__ __launch_bounds__(256, 2) void gemm_relu(
    const u16* __restrict__ A, const u16* __restrict__ Bt,
    const float* __restrict__ bias, __hip_bfloat16* __restrict__ outB,
    int M, int N, int K) {
  __shared__ u16 As[128 * 64];
  __shared__ u16 Bs[128 * 64];
  int tid = threadIdx.x;
  int wave = tid >> 6, lane = tid & 63;
  int wm = wave & 1, wn = wave >> 1;              // 2x2 waves of 64x64
  int m0 = blockIdx.y * 128, n0 = blockIdx.x * 128;
  int lr = lane & 15, lq = lane >> 4;
  int swz = (lr & 7) << 3;                        // read-side XOR (elems)

  vf4 acc[4][4];
#pragma unroll
  for (int i = 0; i < 4; ++i)
#pragma unroll
    for (int j = 0; j < 4; ++j) {
      acc[i][j][0] = 0.f; acc[i][j][1] = 0.f; acc[i][j][2] = 0.f; acc[i][j][3] = 0.f;
    }

  int srow = tid >> 3;                  // 0..31 (+32*r rounds; &7 invariant)
  int sc = (tid & 7) * 8;               // linear LDS dest col (elems)
  int cswz = (((tid & 7) ^ (srow & 7)) * 8);   // pre-swizzled GLOBAL source col
  const u16* ag = A + (size_t)(m0 + srow) * K + cswz;
  const u16* bg = Bt + (size_t)(n0 + srow) * K + cswz;
  u16* al = As + srow * 64 + sc;
  u16* bl = Bs + srow * 64 + sc;
  const size_t rstride32 = (size_t)32 * K;

  for (int k0 = 0; k0 < K; k0 += 64) {
#pragma unroll
    for (int r = 0; r < 4; ++r) {
      gload16(ag + k0 + r * rstride32, al + r * 32 * 64);
      gload16(bg + k0 + r * rstride32, bl + r * 32 * 64);
    }
    __syncthreads();
#pragma unroll
    for (int kk = 0; kk < 2; ++kk) {
      vs8 av[4], bv[4];
#pragma unroll
      for (int i = 0; i < 4; ++i)
        av[i] = *(const vs8*)&As[(wm * 64 + i * 16 + lr) * 64 + ((kk * 32 + lq * 8) ^ swz)];
#pragma unroll
      for (int j = 0; j < 4; ++j)
        bv[j] = *(const vs8*)&Bs[(wn * 64 + j * 16 + lr) * 64 + ((kk * 32 + lq * 8) ^ swz)];
#pragma unroll
      for (int i = 0; i < 4; ++i)
#pragma unroll
        for (int j = 0; j < 4; ++j)
          acc[i][j] = __builtin_amdgcn_mfma_f32_16x16x32_bf16(av[i], bv[j], acc[i][j], 0, 0, 0);
    }
    __syncthreads();
  }

#pragma unroll
  for (int i = 0; i < 4; ++i) {
    int row0 = m0 + wm * 64 + i * 16 + lq * 4;
#pragma unroll
    for (int j = 0; j < 4; ++j) {
      int col = n0 + wn * 64 + j * 16 + lr;
      float bb = bias[col];
#pragma unroll
      for (int r = 0; r < 4; ++r) {
        size_t idx = (size_t)(row0 + r) * N + col;
        outB[idx] = __float2bfloat16(fmaxf(acc[i][j][r] + bb, 0.0f));
      }
    }
  }
}

// ---------------- bf16 MFMA GEMM 64x128, BK=64, LDS-swizzled (qkv): A@W+b -> f16 ----------------
__global__ __launch_bounds__(256, 3) void gemm_qkv64(
    const u16* __restrict__ A, const u16* __restrict__ Bt,
    const float* __restrict__ bias, f16* __restrict__ outH,
    int M, int N, int K) {
  __shared__ u16 As[64 * 64];
  __shared__ u16 Bs[128 * 64];
  int tid = threadIdx.x;
  int wave = tid >> 6, lane = tid & 63;
  int wm = wave & 1, wn = wave >> 1;              // wave = 32 rows x 64 cols
  int m0 = blockIdx.y * 64, n0 = blockIdx.x * 128;
  int lr = lane & 15, lq = lane >> 4;
  int swz = (lr & 7) << 3;

  vf4 acc[2][4];
#pragma unroll
  for (int i = 0; i < 2; ++i)
#pragma unroll
    for (int j = 0; j < 4; ++j) { acc[i][j][0]=0.f; acc[i][j][1]=0.f; acc[i][j][2]=0.f; acc[i][j][3]=0.f; }

  int srow = tid >> 3;                  // 0..31
  int sc = (tid & 7) * 8;
  int cswz = (((tid & 7) ^ (srow & 7)) * 8);
  const u16* ag = A + (size_t)(m0 + srow) * K + cswz;
  const u16* bg = Bt + (size_t)(n0 + srow) * K + cswz;
  u16* al = As + srow * 64 + sc;
  u16* bl = Bs + srow * 64 + sc;
  const size_t rstride32 = (size_t)32 * K;

  for (int k0 = 0; k0 < K; k0 += 64) {
#pragma unroll
    for (int r = 0; r < 2; ++r)
      gload16(ag + k0 + r * rstride32, al + r * 32 * 64);
#pragma unroll
    for (int r = 0; r < 4; ++r)
      gload16(bg + k0 + r * rstride32, bl + r * 32 * 64);
    __syncthreads();
#pragma unroll
    for (int kk = 0; kk < 2; ++kk) {
      vs8 av[2], bv[4];
#pragma unroll
      for (int i = 0; i < 2; ++i)
        av[i] = *(const vs8*)&As[(wm * 32 + i * 16 + lr) * 64 + ((kk * 32 + lq * 8) ^ swz)];
#pragma unroll
      for (int j = 0; j < 4; ++j)
        bv[j] = *(const vs8*)&Bs[(wn * 64 + j * 16 + lr) * 64 + ((kk * 32 + lq * 8) ^ swz)];
#pragma unroll
      for (int i = 0; i < 2; ++i)
#pragma unroll
        for (int j = 0; j < 4; ++j)
          acc[i][j] = __builtin_amdgcn_mfma_f32_16x16x32_bf16(av[i], bv[j], acc[i][j], 0, 0, 0);
    }
    __syncthreads();
  }

#pragma unroll
  for (int i = 0; i < 2; ++i) {
    int row0 = m0 + wm * 32 + i * 16 + lq * 4;
#pragma unroll
    for (int j = 0; j < 4; ++j) {
      int col = n0 + wn * 64 + j * 16 + lr;
      float bb = bias[col];
#pragma unroll
      for (int r = 0; r < 4; ++r)
        outH[(size_t)(row0 + r) * N + col] = (f16)(acc[i][j][r] + bb);
    }
  }
}

// ---------------- fused GEMM (N=256) + bias + bf16 residual + LN -> bf16 (+f32 opt) ----------------
// 16 rows/block, 256 threads (4 waves, wn 0..3; wave = 16 rows x 64 cols), grid 512 =
// 2 blocks/CU. BK=64 simple barrier loop, XOR-swizzled tiles.
// When OfA != null (LN1): A-staging reads kv-split partials Of[0]+Of[1], scales by precomputed
// 1/(l0+l1), converts to bf16, ds_writes (combine fused; math identical).
__global__ __launch_bounds__(256, 2) void gemm_ln(
    const u16* __restrict__ A, const u16* __restrict__ Bt,
    const float* __restrict__ bias, const __hip_bfloat16* __restrict__ res,
    const float* __restrict__ gam, const float* __restrict__ bet,
    __hip_bfloat16* __restrict__ outB, float* __restrict__ outF, int K,
    const f16* __restrict__ OfA, const float* __restrict__ lf) {
  __shared__ u16 As[16 * 64];
  __shared__ u16 Bs[256 * 64];
  __shared__ float ps[4][16], ps2[4][16], mur[16], rsr[16];
  __shared__ float invs[8][16];                    // 1/(l0+l1) per (head, local row)
  int tid = threadIdx.x;
  int wave = tid >> 6, lane = tid & 63;
  int wn = wave;                                   // 0..3 (single row-group)
  int lr = lane & 15, lq = lane >> 4;
  int m0 = blockIdx.x * 16;
  int swz = (lr & 7) << 3;

  vf4 acc[4];
#pragma unroll
  for (int j = 0; j < 4; ++j) { acc[j][0]=0.f; acc[j][1]=0.f; acc[j][2]=0.f; acc[j][3]=0.f; }

  // A-staging: 16 rows x 64 cols/step = 128 vh8 -> tid<128
  int srA = tid >> 3;                   // 0..31 (A uses 0..15 via tid<128)
  int scA = (tid & 7) * 8;
  int cswzA = (((tid & 7) ^ (srA & 7)) * 8);
  const u16* ag = A + (size_t)(m0 + srA) * K + cswzA;
  u16* al = As + srA * 64 + scA;
  // B-staging: 256 rows x 64 cols/step = 2048 vh8 -> 8 rounds of 32 rows
  const u16* bg = Bt + (size_t)srA * K + cswzA;   // rows srA + 32*r; (srA+32r)&7 == srA&7
  u16* bl = Bs + srA * 64 + scA;

  if (OfA) {
    if (tid < 128) {
      int h = tid >> 4, rl = tid & 15;
      int row = m0 + rl, bb_ = row >> 11, t = row & 2047;
      int g = bb_ * 8 + h;
      invs[h][rl] = 1.0f / (lf[g * 2048 + t] + lf[65536 + g * 2048 + t]);
    }
    __syncthreads();
  }

  for (int k0 = 0; k0 < K; k0 += 64) {
    if (tid < 128) {
      if (OfA) {
        // rows 0..15; logical k-col = k0 + cswzA (pre-swizzled), dest linear
        size_t off = (size_t)(m0 + srA) * 256 + k0 + cswzA;
        vh8 a0 = *(const vh8*)(OfA + off);
        vh8 a1 = *(const vh8*)(OfA + 2097152 + off);
        float inv = invs[(k0 + cswzA) >> 5][srA];
        union { vs8 v; u16 u[8]; } pk;
#pragma unroll
        for (int j = 0; j < 8; ++j) {
          __hip_bfloat16 hb = __float2bfloat16(((float)a0[j] + (float)a1[j]) * inv);
          pk.u[j] = *(u16*)&hb;
        }
        *(vs8*)al = pk.v;
      } else {
        gload16(ag + k0, al);
      }
    }
#pragma unroll
    for (int r = 0; r < 8; ++r)
      gload16(bg + k0 + (size_t)(r * 32) * K, bl + r * 32 * 64);
    __syncthreads();
#pragma unroll
    for (int kk = 0; kk < 2; ++kk) {
      vs8 av, bv[4];
      av = *(const vs8*)&As[lr * 64 + ((kk * 32 + lq * 8) ^ swz)];
#pragma unroll
      for (int j = 0; j < 4; ++j)
        bv[j] = *(const vs8*)&Bs[(wn * 64 + j * 16 + lr) * 64 + ((kk * 32 + lq * 8) ^ swz)];
#pragma unroll
      for (int j = 0; j < 4; ++j)
        acc[j] = __builtin_amdgcn_mfma_f32_16x16x32_bf16(av, bv[j], acc[j], 0, 0, 0);
    }
    __syncthreads();
  }

  float sum_[4], sq_[4];
#pragma unroll
  for (int r = 0; r < 4; ++r) { sum_[r] = 0.f; sq_[r] = 0.f; }
#pragma unroll
  for (int j = 0; j < 4; ++j) {
    int col = wn * 64 + j * 16 + lr;
    float bb = bias[col];
#pragma unroll
    for (int r = 0; r < 4; ++r) {
      int row = m0 + lq * 4 + r;
      float v = acc[j][r] + bb + __bfloat162float(res[(size_t)row * 256 + col]);
      acc[j][r] = v;
      sum_[r] += v;
      sq_[r] += v * v;
    }
  }
#pragma unroll
  for (int r = 0; r < 4; ++r) {
#pragma unroll
    for (int m = 1; m <= 8; m <<= 1) {
      sum_[r] += __shfl_xor(sum_[r], m);
      sq_[r]  += __shfl_xor(sq_[r], m);
    }
  }
  if (lr == 0) {
#pragma unroll
    for (int r = 0; r < 4; ++r) {
      int rl = lq * 4 + r;
      ps[wn][rl] = sum_[r];
      ps2[wn][rl] = sq_[r];
    }
  }
  __syncthreads();
  if (tid < 16) {
    float s = ps[0][tid] + ps[1][tid] + ps[2][tid] + ps[3][tid];
    float s2 = ps2[0][tid] + ps2[1][tid] + ps2[2][tid] + ps2[3][tid];
    float mu = s * (1.0f / 256.0f);
    float var = s2 * (1.0f / 256.0f) - mu * mu;
    mur[tid] = mu;
    rsr[tid] = rsqrtf(var + 1e-5f);
  }
  __syncthreads();
#pragma unroll
  for (int r = 0; r < 4; ++r) {
    int rl = lq * 4 + r;
    float mu = mur[rl], rs = rsr[rl];
    int row = m0 + rl;
#pragma unroll
    for (int j = 0; j < 4; ++j) {
      int col = wn * 64 + j * 16 + lr;
      float o = (acc[j][r] - mu) * rs * gam[col] + bet[col];
      size_t idx = (size_t)row * 256 + col;
      outB[idx] = __float2bfloat16(o);
      if (outF) outF[idx] = o;
    }
  }
}

// ---------------- MFMA flash attention v7: kv-split 2, + setprio on MFMA cluster ----------------
// No running max is tracked (bounded logits -> raw exp2), so partials combine ADDITIVELY:
// O = O0+O1, l = l0+l1. Grid 512 -> 2 blocks/CU. Partials are normalized inside gemm_ln (LN1).
__global__ __launch_bounds__(512, 4) void attn_mfma(const f16* __restrict__ qkv,
                                                    f16* __restrict__ Of,
                                                    float* __restrict__ lf) {
  // per buf: K [128][40] u16 = 5120 | VT [32][132] f16 = 4224 -> 9344 u16; x2 bufs = 37376 B
  __shared__ __align__(16) u16 lds[2][9344];
  int tid = threadIdx.x;
  int wave = tid >> 6, lane = tid & 63;
  int lr = lane & 15, quad = lane >> 4;

  int id = blockIdx.x;
  int xcd = id & 7, slot = id >> 3;                // slot 0..63
  int grp = xcd * 4 + (slot & 3);                  // 32 (b,h) groups
  int qt = (slot >> 2) & 7;                        // 8 q-tiles of 256 rows
  int split = slot >> 5;                           // kv half: 0 or 1
  int b = grp >> 3, h = grp & 7;
  int q0 = qt * 256;
  int kv0 = split << 10;                           // 0 or 1024
  int rowbase = b * 2048;
  const f16* base_bh = qkv + (size_t)rowbase * 768 + h * 96;

  vh8 qf[2];
#pragma unroll
  for (int nt = 0; nt < 2; ++nt) {
    int qr = q0 + wave * 32 + nt * 16 + lr;
    vh8 t = *(const vh8*)(base_bh + (size_t)qr * 768 + quad * 8);
#pragma unroll
    for (int j = 0; j < 8; ++j) t[j] = t[j] * (f16)0.25508682f;
    qf[nt] = t;
  }

  vf4 O[2][2], lO[2];
#pragma unroll
  for (int a = 0; a < 2; ++a) {
    lO[a][0]=0.f; lO[a][1]=0.f; lO[a][2]=0.f; lO[a][3]=0.f;
#pragma unroll
    for (int d = 0; d < 2; ++d) { O[a][d][0]=0.f; O[a][d][1]=0.f; O[a][d][2]=0.f; O[a][d][3]=0.f; }
  }

  // staging maps: all 512 threads stage K (1 vh8) and V (2 vh4 -> 4 vh2) per chunk
  int srK = tid >> 2;                  // 0..127
  int scK = (tid & 3) * 8;
  const f16* kg = base_bh + (size_t)(kv0 + srK) * 768 + 32 + scK;
  int kvp = tid >> 3;                  // 0..63 -> rows 2kvp, 2kvp+1
  int d4 = (tid & 7) * 4;
  const f16* vg = base_bh + (size_t)(kv0 + kvp * 2) * 768 + 64 + d4;

  const vf4 z4 = {0.f, 0.f, 0.f, 0.f};
  const vh4 onesh = {(f16)1.0f, (f16)1.0f, (f16)1.0f, (f16)1.0f};
  const size_t cstep = (size_t)128 * 768;

  // stage chunk 0 into buf 0
  {
    vh8 k0 = *(const vh8*)kg;
    *(vh8*)&lds[0][srK * 40 + scK] = k0;
    vh4 a = *(const vh4*)vg;
    vh4 bb = *(const vh4*)(vg + 768);
    f16* vt0 = (f16*)&lds[0][5120];
#pragma unroll
    for (int i = 0; i < 4; ++i) {
      vh2 pr; pr[0] = a[i]; pr[1] = bb[i];
      *(vh2*)(vt0 + (d4 + i) * 132 + kvp * 2) = pr;
    }
  }
  __syncthreads();

  for (int c = 0; c < 8; ++c) {        // 8 chunks of 128 kv rows (this split's half)
    int cur = c & 1;
    const f16* Ks = (const f16*)&lds[cur][0];
    const f16* VT = (const f16*)&lds[cur][5120];

    vh8 kn; vh4 va, vb;
    if (c < 7) {                       // prefetch next chunk (hidden under 8-t16 compute)
      kn = *(const vh8*)(kg + (size_t)(c + 1) * cstep);
      const f16* vp = vg + (size_t)(c + 1) * cstep;
      va = *(const vh4*)vp;
      vb = *(const vh4*)(vp + 768);
    }

    __builtin_amdgcn_s_setprio(1);     // T5: favor this wave while in the MFMA/exp cluster
#pragma unroll
    for (int t16 = 0; t16 < 8; ++t16) {
      vh8 ak = *(const vh8*)&Ks[(t16 * 16 + lr) * 40 + quad * 8];
      vf4 s0 = __builtin_amdgcn_mfma_f32_16x16x32_f16(ak, qf[0], z4, 0, 0, 0);
      vf4 s1 = __builtin_amdgcn_mfma_f32_16x16x32_f16(ak, qf[1], z4, 0, 0, 0);
      vh4 p0, p1;
      ((hw2*)&p0)[0] = __builtin_amdgcn_cvt_pkrtz(fexp2(s0[0]), fexp2(s0[1]));
      ((hw2*)&p0)[1] = __builtin_amdgcn_cvt_pkrtz(fexp2(s0[2]), fexp2(s0[3]));
      ((hw2*)&p1)[0] = __builtin_amdgcn_cvt_pkrtz(fexp2(s1[0]), fexp2(s1[1]));
      ((hw2*)&p1)[1] = __builtin_amdgcn_cvt_pkrtz(fexp2(s1[2]), fexp2(s1[3]));
      vh4 vf0 = *(const vh4*)&VT[(0 * 16 + lr) * 132 + t16 * 16 + quad * 4];
      vh4 vf1 = *(const vh4*)&VT[(1 * 16 + lr) * 132 + t16 * 16 + quad * 4];
      O[0][0] = __builtin_amdgcn_mfma_f32_16x16x16f16(p0, vf0, O[0][0], 0, 0, 0);
      O[0][1] = __builtin_amdgcn_mfma_f32_16x16x16f16(p0, vf1, O[0][1], 0, 0, 0);
      O[1][0] = __builtin_amdgcn_mfma_f32_16x16x16f16(p1, vf0, O[1][0], 0, 0, 0);
      O[1][1] = __builtin_amdgcn_mfma_f32_16x16x16f16(p1, vf1, O[1][1], 0, 0, 0);
      lO[0] = __builtin_amdgcn_mfma_f32_16x16x16f16(p0, onesh, lO[0], 0, 0, 0);
      lO[1] = __builtin_amdgcn_mfma_f32_16x16x16f16(p1, onesh, lO[1], 0, 0, 0);
    }
    __builtin_amdgcn_s_setprio(0);

    if (c < 7) {                       // write prefetched chunk into the other buffer
      *(vh8*)&lds[cur ^ 1][srK * 40 + scK] = kn;
      f16* vt1 = (f16*)&lds[cur ^ 1][5120];
#pragma unroll
      for (int i = 0; i < 4; ++i) {
        vh2 pr; pr[0] = va[i]; pr[1] = vb[i];
        *(vh2*)(vt1 + (d4 + i) * 132 + kvp * 2) = pr;
      }
    }
    __syncthreads();
  }

  // epilogue: write UNNORMALIZED partial O (f16) + row-sum l (f32); LN1 normalizes
#pragma unroll
  for (int nt = 0; nt < 2; ++nt) {
#pragma unroll
    for (int r = 0; r < 4; ++r) {
      int tq = q0 + wave * 32 + nt * 16 + quad * 4 + r;    // t index 0..2047
      if (lr == 0) lf[split * 65536 + grp * 2048 + tq] = lO[nt][r];
      int row = rowbase + tq;
#pragma unroll
      for (int dt = 0; dt < 2; ++dt) {
        int col = h * 32 + dt * 16 + lr;
        Of[(size_t)split * 2097152 + (size_t)row * 256 + col] = (f16)O[nt][dt][r];
      }
    }
  }
}

// ---------------- driver ----------------
extern "C" void kernel_launch(void* const* d_in, const int* in_sizes, int n_in,
                              void* d_out, int out_size, void* d_ws, size_t ws_size,
                              hipStream_t stream) {
  (void)in_sizes; (void)n_in; (void)out_size; (void)ws_size;
  const float* x     = (const float*)d_in[0];
  const float* qkv_b = (const float*)d_in[2];
  const float* out_b = (const float*)d_in[4];
  const float* ff1_b = (const float*)d_in[6];
  const float* ff2_b = (const float*)d_in[8];
  const float* ln1_g = (const float*)d_in[9];
  const float* ln1_b = (const float*)d_in[10];
  const float* ln2_g = (const float*)d_in[11];
  const float* ln2_b = (const float*)d_in[12];

  // ws layout (bytes); total = 44,040,192
  //   [0, 8388608)          Of: attn partial O f16 [2][8192][256] (dead by ff1)
  //   [8388608, 12582912)   Xb: bf16 carried state (4 MB)
  //   [12582912, 13107200)  lf: attn partial l f32 [2][32][2048] (512 KB)
  //   [25165824, 37748736)  qkvH f16 8192x768 (12.6 MB)
  //   [20971520, 37748736)  hB bf16 ff1-out (16.8 MB) overlaps qkvH (dead by ff1)
  //   [37748736, 44040192)  transposed bf16 weights
  char* ws = (char*)d_ws;
  f16*            Of    = (f16*)(ws + 0);
  __hip_bfloat16* Xb    = (__hip_bfloat16*)(ws + 8388608);
  float*          lf    = (float*)(ws + 12582912);
  f16*            qkvH  = (f16*)(ws + 25165824);
  __hip_bfloat16* hB    = (__hip_bfloat16*)(ws + 20971520);
  u16* qkvwT = (u16*)(ws + 37748736);  // [L][768][256] bf16
  u16* outwT = (u16*)(ws + 39321600);  // [L][256][256] bf16
  u16* ff1wT = (u16*)(ws + 39845888);  // [L][1024][256] bf16
  u16* ff2wT = (u16*)(ws + 41943040);  // [L][256][1024] bf16  ends 44,040,192

  pe_kernel<<<2048, 256, 0, stream>>>(x, Xb);
  transpose_cast_all<<<3072, dim3(32, 8), 0, stream>>>(
      (const float*)d_in[1], (const float*)d_in[3], (const float*)d_in[5], (const float*)d_in[7],
      qkvwT, outwT, ff1wT, ff2wT);

  for (int l = 0; l < 4; ++l) {
    // qkv = x @ qkv_w + b -> f16 (64x128 tile, 768 blocks = 3/CU)
    gemm_qkv64<<<dim3(6, 128), 256, 0, stream>>>((const u16*)Xb, qkvwT + (size_t)l * 768 * 256,
        qkv_b + l * 768, qkvH, 8192, 768, 256);
    // attn partials (kv-split 2, 2 blocks/CU, XCD-pinned)
    attn_mfma<<<512, 512, 0, stream>>>(qkvH, Of, lf);
    // Xb = LN1((O0+O1)/l @ out_w + b + Xb)  -- combine fused into A-staging; 16-row blocks
    gemm_ln<<<512, 256, 0, stream>>>(nullptr, outwT + (size_t)l * 256 * 256,
        out_b + l * 256, Xb, ln1_g + l * 256, ln1_b + l * 256, Xb, nullptr, 256, Of, lf);
    // h = relu(Xb @ W1 + b1) -> bf16
    gemm_relu<<<dim3(8, 64), 256, 0, stream>>>((const u16*)Xb, ff1wT + (size_t)l * 1024 * 256,
        ff1_b + l * 1024, hB, 8192, 1024, 256);
    // Xb = LN2(h @ W2 + b2 + Xb); last layer also writes d_out f32; 16-row blocks
    float* lnout = (l == 3) ? (float*)d_out : nullptr;
    gemm_ln<<<512, 256, 0, stream>>>((const u16*)hB, ff2wT + (size_t)l * 256 * 1024,
        ff2_b + l * 256, Xb, ln2_g + l * 256, ln2_b + l * 256, Xb, lnout, 1024, nullptr, nullptr);
  }
}